// Round 10
// baseline (650.932 us; speedup 1.0000x reference)
//
#include <hip/hip_runtime.h>
#include <hip/hip_cooperative_groups.h>

namespace cg = cooperative_groups;

typedef unsigned short u16;
typedef unsigned int u32;
typedef __bf16 bf16x8 __attribute__((ext_vector_type(8)));
typedef float f32x4 __attribute__((ext_vector_type(4)));

__device__ __forceinline__ u16 f2bf(float f) {
    union { float f; u32 u; } v; v.f = f;
    u32 r = v.u + 0x7FFFu + ((v.u >> 16) & 1u);   // RNE
    return (u16)(r >> 16);
}
__device__ __forceinline__ float bf2f(u16 h) {
    union { u32 u; float f; } v; v.u = (u32)h << 16; return v.f;
}

// ---------------------------------------------------------------------------
// bf16 GEMM: C = A @ Bt^T (+bias). 128x128 tile, BK=64, XOR-swizzled LDS.
// ---------------------------------------------------------------------------
__global__ __launch_bounds__(256) void gemm_bt(
    const u16* __restrict__ A, const u16* __restrict__ Bt,
    float* __restrict__ C, u16* __restrict__ Cb, const float* __restrict__ bias,
    int M, int N, int K, int relu)
{
    __shared__ char lA[128 * 64 * 2];
    __shared__ char lB[128 * 64 * 2];
    const int t = threadIdx.x;
    const int w = t >> 6, l = t & 63;
    const int bn = blockIdx.x, bm = blockIdx.y;
    const int wr = w >> 1, wc = w & 1;

    const int srow = w * 8 + (l >> 3);
    const int scol = ((l & 7) ^ (l >> 3)) << 3;
    const u16* gA = A + (size_t)(bm * 128 + srow) * K + scol;
    const u16* gB = Bt + (size_t)(bn * 128 + srow) * K + scol;

    f32x4 zero = {0.f, 0.f, 0.f, 0.f};
    f32x4 acc[4][4];
#pragma unroll
    for (int i = 0; i < 4; i++)
#pragma unroll
        for (int j = 0; j < 4; j++) acc[i][j] = zero;

    const int arow = wr * 64 + (l & 15);
    const int brow = wc * 64 + (l & 15);
    const int kx = l >> 4;
    const int sw = l & 7;

    for (int k0 = 0; k0 < K; k0 += 64) {
#pragma unroll
        for (int c2 = 0; c2 < 4; ++c2) {
            __builtin_amdgcn_global_load_lds(
                (const __attribute__((address_space(1))) void*)(gA + (size_t)c2 * 32 * K + k0),
                (__attribute__((address_space(3))) void*)(lA + c2 * 4096 + w * 1024), 16, 0, 0);
            __builtin_amdgcn_global_load_lds(
                (const __attribute__((address_space(1))) void*)(gB + (size_t)c2 * 32 * K + k0),
                (__attribute__((address_space(3))) void*)(lB + c2 * 4096 + w * 1024), 16, 0, 0);
        }
        __syncthreads();
#pragma unroll
        for (int kk = 0; kk < 2; ++kk) {
            bf16x8 af[4], bfr[4];
#pragma unroll
            for (int mi = 0; mi < 4; ++mi)
                af[mi] = *(const bf16x8*)(lA + (arow + mi * 16) * 128 + (((kk * 4 + kx) ^ sw) << 4));
#pragma unroll
            for (int ni = 0; ni < 4; ++ni)
                bfr[ni] = *(const bf16x8*)(lB + (brow + ni * 16) * 128 + (((kk * 4 + kx) ^ sw) << 4));
#pragma unroll
            for (int mi = 0; mi < 4; ++mi)
#pragma unroll
                for (int ni = 0; ni < 4; ++ni)
                    acc[mi][ni] = __builtin_amdgcn_mfma_f32_16x16x32_bf16(af[mi], bfr[ni], acc[mi][ni], 0, 0, 0);
        }
        __syncthreads();
    }

    const int cm = bm * 128 + wr * 64;
    const int cn = bn * 128 + wc * 64;
#pragma unroll
    for (int mi = 0; mi < 4; ++mi) {
#pragma unroll
        for (int ni = 0; ni < 4; ++ni) {
            int row0 = cm + mi * 16 + (l >> 4) * 4;
            int col = cn + ni * 16 + (l & 15);
            float bv = bias ? bias[col] : 0.f;
#pragma unroll
            for (int r = 0; r < 4; ++r) {
                float v = acc[mi][ni][r] + bv;
                if (relu) v = fmaxf(v, 0.f);
                if (Cb) Cb[(size_t)(row0 + r) * N + col] = f2bf(v);
                else    C [(size_t)(row0 + r) * N + col] = v;
            }
        }
    }
}

// ---------------------------------------------------------------------------
// Split-K GEMM body (device fn, LDS passed in) + standalone kernel wrapper.
// P[ks][M][N] = A[:, ks*Kc:(ks+1)*Kc] @ Bt slice.
// ---------------------------------------------------------------------------
__device__ __forceinline__ void gemm_sk_body(
    const u16* __restrict__ A, const u16* __restrict__ Bt, float* __restrict__ P,
    int M, int N, int K, int Kc, int bn, int bm, int ks, char* lsmem)
{
    char* lA = lsmem;
    char* lB = lsmem + 32768;
    const int t = threadIdx.x;
    const int w = t >> 6, l = t & 63;
    const int wr = w >> 1, wc = w & 1;

    const int srow = w * 8 + (l >> 3);
    const int scol = ((l & 7) ^ (l >> 3)) << 3;
    const u16* gA = A + (size_t)(bm * 128 + srow) * K + scol;
    const u16* gB = Bt + (size_t)(bn * 128 + srow) * K + scol;

    f32x4 zero = {0.f, 0.f, 0.f, 0.f};
    f32x4 acc[4][4];
#pragma unroll
    for (int i = 0; i < 4; i++)
#pragma unroll
        for (int j = 0; j < 4; j++) acc[i][j] = zero;

    const int arow = wr * 64 + (l & 15);
    const int brow = wc * 64 + (l & 15);
    const int kx = l >> 4;
    const int sw = l & 7;

    const int kbeg = ks * Kc, kend = kbeg + Kc;
    for (int k0 = kbeg; k0 < kend; k0 += 64) {
#pragma unroll
        for (int c2 = 0; c2 < 4; ++c2) {
            __builtin_amdgcn_global_load_lds(
                (const __attribute__((address_space(1))) void*)(gA + (size_t)c2 * 32 * K + k0),
                (__attribute__((address_space(3))) void*)(lA + c2 * 4096 + w * 1024), 16, 0, 0);
            __builtin_amdgcn_global_load_lds(
                (const __attribute__((address_space(1))) void*)(gB + (size_t)c2 * 32 * K + k0),
                (__attribute__((address_space(3))) void*)(lB + c2 * 4096 + w * 1024), 16, 0, 0);
        }
        __syncthreads();
#pragma unroll
        for (int kk = 0; kk < 2; ++kk) {
            bf16x8 af[4], bfr[4];
#pragma unroll
            for (int mi = 0; mi < 4; ++mi)
                af[mi] = *(const bf16x8*)(lA + (arow + mi * 16) * 128 + (((kk * 4 + kx) ^ sw) << 4));
#pragma unroll
            for (int ni = 0; ni < 4; ++ni)
                bfr[ni] = *(const bf16x8*)(lB + (brow + ni * 16) * 128 + (((kk * 4 + kx) ^ sw) << 4));
#pragma unroll
            for (int mi = 0; mi < 4; ++mi)
#pragma unroll
                for (int ni = 0; ni < 4; ++ni)
                    acc[mi][ni] = __builtin_amdgcn_mfma_f32_16x16x32_bf16(af[mi], bfr[ni], acc[mi][ni], 0, 0, 0);
        }
        __syncthreads();
    }

    float* Pp = P + (size_t)ks * M * N;
    const int cm = bm * 128 + wr * 64;
    const int cn = bn * 128 + wc * 64;
#pragma unroll
    for (int mi = 0; mi < 4; ++mi) {
#pragma unroll
        for (int ni = 0; ni < 4; ++ni) {
            int row0 = cm + mi * 16 + (l >> 4) * 4;
            int col = cn + ni * 16 + (l & 15);
#pragma unroll
            for (int r = 0; r < 4; ++r)
                Pp[(size_t)(row0 + r) * N + col] = acc[mi][ni][r];
        }
    }
}

__global__ __launch_bounds__(256) void gemm_bt_sk(
    const u16* __restrict__ A, const u16* __restrict__ Bt,
    float* __restrict__ P, int M, int N, int K, int Kc)
{
    __shared__ char lsmem[65536];
    gemm_sk_body(A, Bt, P, M, N, K, Kc, blockIdx.x, blockIdx.y, blockIdx.z, lsmem);
}

// sum KS partials + bias, optional relu, write bf16
__global__ void sk_reduce_b(const float* __restrict__ P, int KS, long MN, int N,
                            const float* __restrict__ bias, int relu, u16* __restrict__ outb)
{
    long i = (long)blockIdx.x * blockDim.x + threadIdx.x;
    long stride = (long)gridDim.x * blockDim.x;
    for (; i < MN; i += stride) {
        float v = bias ? bias[i % N] : 0.f;
        for (int ks = 0; ks < KS; ks++) v += P[(size_t)ks * MN + i];
        if (relu) v = fmaxf(v, 0.f);
        outb[i] = f2bf(v);
    }
}

// ---------------------------------------------------------------------------
// weight conversion (6 jobs)
struct CJob { const float* src; u16* dst; long n4; };
struct CJobs6 { CJob j[6]; };
__global__ void conv6_bf16(CJobs6 jobs)
{
    CJob jb = jobs.j[blockIdx.z];
    long i = (long)blockIdx.x * blockDim.x + threadIdx.x;
    long stride = (long)gridDim.x * blockDim.x;
    for (; i < jb.n4; i += stride) {
        float4 v = ((const float4*)jb.src)[i];
        ushort4 o;
        o.x = f2bf(v.x); o.y = f2bf(v.y); o.z = f2bf(v.z); o.w = f2bf(v.w);
        ((ushort4*)jb.dst)[i] = o;
    }
}

// transpose (z=0,1) + bc_prep (z=2) fused
struct TJob { const float* src; u16* dst; int Rr, Cc, ldo; };
__global__ void prep2(TJob j0, TJob j1, const float* __restrict__ b_rgcn,
                      const float* __restrict__ wg_rel, const float* __restrict__ wg_root,
                      float* __restrict__ bc)
{
    if (blockIdx.z == 2) {
        if (blockIdx.x == 0 && blockIdx.y == 0 && threadIdx.x < 128) {
            int n = threadIdx.x;
            const float* W = (n < 64) ? (wg_rel + n) : (wg_root + (n - 64));
            float s = 0.f;
            for (int k = 0; k < 768; k++) s += b_rgcn[k] * W[(size_t)k * 64];
            bc[n] = s;
        }
        return;
    }
    TJob jb = blockIdx.z ? j1 : j0;
    __shared__ float tile[32][33];
    int tx = threadIdx.x & 31, ty = threadIdx.x >> 5;
    int c0 = blockIdx.x * 32, r0 = blockIdx.y * 32;
    if (c0 >= jb.Cc || r0 >= jb.Rr) return;
    for (int dy = 0; dy < 32; dy += 8) {
        int r = r0 + ty + dy, c = c0 + tx;
        tile[ty + dy][tx] = (r < jb.Rr && c < jb.Cc) ? jb.src[(size_t)r * jb.Cc + c] : 0.f;
    }
    __syncthreads();
    for (int dy = 0; dy < 32; dy += 8) {
        int c = c0 + ty + dy, r = r0 + tx;
        if (c < jb.Cc && r < jb.Rr) jb.dst[(size_t)c * jb.ldo + r] = f2bf(tile[tx][ty + dy]);
    }
}

// nodes -> Abig cols 0:768 (blocks <2048) + gather_x0 (blocks >=2048)
__global__ void conv_nodes_gx(const float* __restrict__ nodes, u16* __restrict__ Abig,
                              int Nn, int Mpad, const int* __restrict__ opt,
                              float* __restrict__ x0, u16* __restrict__ x0b)
{
    int b = blockIdx.x;
    if (b < 2048) {
        long i = (long)b * 256 + threadIdx.x;
        long stride = 2048L * 256;
        long n4 = (long)Mpad * 192;
        for (; i < n4; i += stride) {
            long row = i / 192, c4 = i % 192;
            ushort4 o;
            if ((int)row < Nn) {
                float4 v = ((const float4*)nodes)[i];
                o.x = f2bf(v.x); o.y = f2bf(v.y); o.z = f2bf(v.z); o.w = f2bf(v.w);
            } else { o.x = 0; o.y = 0; o.z = 0; o.w = 0; }
            ((ushort4*)Abig)[row * 384 + c4] = o;
        }
    } else {
        int r = b - 2048;
        size_t srcb = (size_t)opt[r] * 768;
        for (int c = threadIdx.x; c < 768; c += 256) {
            float v = nodes[srcb + c];
            x0[(size_t)r * 768 + c] = v;
            x0b[(size_t)r * 768 + c] = f2bf(v);
        }
    }
}

// ---------------------------------------------------------------------------
// enc1 phase bodies (device fns, LDS passed in)
__device__ __forceinline__ void attn_body(
    const float* __restrict__ Pq, int KS, const float* __restrict__ b_qkv1,
    u16* __restrict__ atnob, int bh, char* lsmem)
{
    float* Q  = (float*)lsmem;
    float* Kk = Q + 4 * 384;
    float* V  = Kk + 4 * 384;
    int b = bh >> 1, h = bh & 1;
    int w = threadIdx.x >> 6, l = threadIdx.x & 63;
    int row = b * 4 + w;
    const int hb = h * 384;
#pragma unroll
    for (int j = 0; j < 6; j++) {
        int c = hb + j * 64 + l;
        float q = b_qkv1[c], k = b_qkv1[768 + c], v = b_qkv1[1536 + c];
        for (int ks = 0; ks < KS; ks++) {
            const float* Pr = Pq + (size_t)ks * 256 * 2304 + (size_t)row * 2304;
            q += Pr[c]; k += Pr[768 + c]; v += Pr[1536 + c];
        }
        Q[w * 384 + j * 64 + l] = q;
        Kk[w * 384 + j * 64 + l] = k;
        V[w * 384 + j * 64 + l] = v;
    }
    __syncthreads();
    float sc[4];
#pragma unroll
    for (int sj = 0; sj < 4; sj++) {
        float p = 0.f;
#pragma unroll
        for (int j = 0; j < 6; j++) p += Q[w * 384 + j * 64 + l] * Kk[sj * 384 + j * 64 + l];
        for (int off = 32; off; off >>= 1) p += __shfl_down(p, off, 64);
        sc[sj] = __shfl(p, 0, 64) * 0.05103103630798287f;   // 1/sqrt(384)
    }
    float mx = fmaxf(fmaxf(sc[0], sc[1]), fmaxf(sc[2], sc[3]));
    float e0 = __expf(sc[0] - mx), e1 = __expf(sc[1] - mx);
    float e2 = __expf(sc[2] - mx), e3 = __expf(sc[3] - mx);
    float inv = 1.f / (e0 + e1 + e2 + e3);
    e0 *= inv; e1 *= inv; e2 *= inv; e3 *= inv;
#pragma unroll
    for (int j = 0; j < 6; j++) {
        int c = j * 64 + l;
        float o = e0 * V[c] + e1 * V[384 + c] + e2 * V[2 * 384 + c] + e3 * V[3 * 384 + c];
        atnob[(size_t)row * 768 + hb + c] = f2bf(o);
    }
    __syncthreads();
}

__device__ __forceinline__ void ln_body(
    const float* __restrict__ P, int KS, const float* __restrict__ bias,
    const float* __restrict__ res, const float* __restrict__ g, const float* __restrict__ be,
    float* __restrict__ outf, u16* __restrict__ outb, const int* __restrict__ opt,
    int ldo, int r, char* lsmem)
{
    float* ss = (float*)lsmem;
    float* qq = ss + 4;
    int t = threadIdx.x;
    float v[3]; float s = 0.f, q = 0.f;
#pragma unroll
    for (int i = 0; i < 3; i++) {
        int c = t + i * 256;
        float a = bias[c] + res[(size_t)r * 768 + c];
        for (int ks = 0; ks < KS; ks++) a += P[(size_t)ks * 256 * 768 + (size_t)r * 768 + c];
        v[i] = a; s += a; q += a * a;
    }
    for (int off = 32; off; off >>= 1) { s += __shfl_down(s, off, 64); q += __shfl_down(q, off, 64); }
    int w = t >> 6, l = t & 63;
    if (l == 0) { ss[w] = s; qq[w] = q; }
    __syncthreads();
    s = ss[0] + ss[1] + ss[2] + ss[3];
    q = qq[0] + qq[1] + qq[2] + qq[3];
    float m = s * (1.f / 768.f);
    float ri = rsqrtf(q * (1.f / 768.f) - m * m + 1e-5f);
    size_t ob = opt ? (size_t)opt[r] * ldo : (size_t)r * ldo;
#pragma unroll
    for (int i = 0; i < 3; i++) {
        int c = t + i * 256;
        float o = g[c] * (v[i] - m) * ri + be[c];
        if (outf) outf[(size_t)r * 768 + c] = o;
        if (outb) outb[ob + c] = f2bf(o);
    }
    __syncthreads();   // guard LDS reuse across row-loop iterations
}

// ---------------------------------------------------------------------------
// enc1_coop: whole encoder layer 1 in ONE cooperative launch (144 x 256).
// Replaces 8 dispatches (round-9: gaps dominated; kernels sum ~45us).
struct Enc1Args {
    const u16 *x0b, *wqkv1b, *wo1b, *wff1ab, *wff1bb;
    const float *b_qkv1, *b_o1, *g1a, *bb1a, *bf1a, *bf1b, *g1b, *bb1b, *x0;
    float *Psk, *x1;
    u16 *x1b, *atnob, *ffhb, *Abig;
    const int* opt;
};

__global__ __launch_bounds__(256) void enc1_coop(Enc1Args a)
{
    cg::grid_group grid = cg::this_grid();
    __shared__ char lsmem[65536];
    const int vb = blockIdx.x;

    // A: qkv = x0b @ wqkv1^T : 256x2304, K=768, KS=4 (18,2,4)=144
    if (vb < 144)
        gemm_sk_body(a.x0b, a.wqkv1b, a.Psk, 256, 2304, 768, 192,
                     vb % 18, (vb / 18) & 1, vb / 36, lsmem);
    grid.sync();
    // B: attention (64 batches x 2 heads = 128)
    if (vb < 128) attn_body(a.Psk, 4, a.b_qkv1, a.atnob, vb, lsmem);
    grid.sync();
    // C: o-proj: 256x768, K=768, KS=4 (6,2,4)=48
    if (vb < 48)
        gemm_sk_body(a.atnob, a.wo1b, a.Psk, 256, 768, 768, 192,
                     vb % 6, (vb / 6) & 1, vb / 12, lsmem);
    grid.sync();
    // D: LN1 (+bf16)
    for (int r = vb; r < 256; r += gridDim.x)
        ln_body(a.Psk, 4, a.b_o1, a.x0, a.g1a, a.bb1a, a.x1, a.x1b, nullptr, 768, r, lsmem);
    grid.sync();
    // E: ff1a: 256x2048, K=768, KS=4 (16,2,4)=128
    if (vb < 128)
        gemm_sk_body(a.x1b, a.wff1ab, a.Psk, 256, 2048, 768, 192,
                     vb % 16, (vb / 16) & 1, vb / 32, lsmem);
    grid.sync();
    // F: relu-reduce -> ffhb
    {
        long MN = 256L * 2048;
        long step = (long)gridDim.x * 256;
        for (long i = (long)vb * 256 + threadIdx.x; i < MN; i += step) {
            float v = a.bf1a[i & 2047];
            for (int ks = 0; ks < 4; ks++) v += a.Psk[(size_t)ks * MN + i];
            a.ffhb[i] = f2bf(fmaxf(v, 0.f));
        }
    }
    grid.sync();
    // G: ff1b: 256x768, K=2048, KS=8 (6,2,8)=96
    if (vb < 96)
        gemm_sk_body(a.ffhb, a.wff1bb, a.Psk, 256, 768, 2048, 256,
                     vb % 6, (vb / 6) & 1, vb / 12, lsmem);
    grid.sync();
    // H: LN2 -> bf16 directly into Abig opt rows
    for (int r = vb; r < 256; r += gridDim.x)
        ln_body(a.Psk, 8, a.bf1b, a.x1, a.g1b, a.bb1b, nullptr, a.Abig, a.opt, 1536, r, lsmem);
}

// ---------------------------------------------------------------------------
// csr_coop: zero + count + 2-level scan + fill in ONE cooperative launch.
struct CsrArgs { const int* ei; int *cnt, *offs, *cur, *elist, *btot; int Nn, E; };

__global__ __launch_bounds__(1024) void csr_coop(CsrArgs a)
{
    cg::grid_group grid = cg::this_grid();
    __shared__ int sc[1024];
    int t = threadIdx.x;
    int gt = blockIdx.x * 1024 + t;
    int GT = gridDim.x * 1024;

    for (int i = gt; i < a.Nn; i += GT) a.cnt[i] = 0;
    grid.sync();
    for (int e = gt; e < a.E; e += GT) atomicAdd(&a.cnt[a.ei[a.E + e]], 1);
    grid.sync();
    int nb = (a.Nn + 1023) >> 10;
    int v = 0;
    if ((int)blockIdx.x < nb) {
        v = (gt < a.Nn) ? a.cnt[gt] : 0;
        sc[t] = v;
        __syncthreads();
        for (int off = 1; off < 1024; off <<= 1) {
            int x = (t >= off) ? sc[t - off] : 0;
            __syncthreads();
            sc[t] += x;
            __syncthreads();
        }
        if (gt < a.Nn) a.offs[gt] = sc[t] - v;       // block-local exclusive
        if (t == 1023) a.btot[blockIdx.x] = sc[1023];
    }
    grid.sync();
    if (blockIdx.x == 0 && t == 0) {
        int run = 0;
        for (int b = 0; b < nb; b++) { int x = a.btot[b]; a.btot[b] = run; run += x; }
    }
    grid.sync();
    if ((int)blockIdx.x < nb && gt < a.Nn) {
        int o = a.offs[gt] + a.btot[blockIdx.x];
        a.offs[gt] = o;
        a.cur[gt] = o;
    }
    grid.sync();
    for (int e = gt; e < a.E; e += GT) {
        int d = a.ei[a.E + e];
        int p = atomicAdd(&a.cur[d], 1);
        a.elist[p] = a.ei[e];
    }
}

// ---------------------------------------------------------------------------
// aggN[d] = mean over in-edges of nodes2[src] -> Abig cols 768:1536 (bf16)
__global__ __launch_bounds__(256) void gather_mean(
    const int* __restrict__ offs, const int* __restrict__ cnt, const int* __restrict__ elist,
    u16* Abig, int Nn, int Mpad)
{
    int w = threadIdx.x >> 6, l = threadIdx.x & 63;
    int d = blockIdx.x * 4 + w;
    if (d >= Mpad) return;
    float acc[12];
#pragma unroll
    for (int j = 0; j < 12; j++) acc[j] = 0.f;
    float inv = 0.f;
    if (d < Nn) {
        int base = offs[d], c = cnt[d];
        for (int i = 0; i < c; i++) {
            int s = elist[base + i];
            const ushort4* p = (const ushort4*)(Abig + (size_t)s * 1536);
#pragma unroll
            for (int j4 = 0; j4 < 3; j4++) {
                ushort4 v = p[j4 * 64 + l];
                acc[j4 * 4 + 0] += bf2f(v.x);
                acc[j4 * 4 + 1] += bf2f(v.y);
                acc[j4 * 4 + 2] += bf2f(v.z);
                acc[j4 * 4 + 3] += bf2f(v.w);
            }
        }
        inv = 1.f / (float)max(c, 1);
    }
    ushort4* q = (ushort4*)(Abig + (size_t)d * 1536 + 768);
#pragma unroll
    for (int j4 = 0; j4 < 3; j4++) {
        ushort4 o;
        o.x = f2bf(acc[j4 * 4 + 0] * inv);
        o.y = f2bf(acc[j4 * 4 + 1] * inv);
        o.z = f2bf(acc[j4 * 4 + 2] * inv);
        o.w = f2bf(acc[j4 * 4 + 3] * inv);
        q[j4 * 64 + l] = o;
    }
}

// ---------------------------------------------------------------------------
// enc2_head: out2 readout + qkv + attn + o-proj + LN(g2a) -> x21 [256,64]
__global__ __launch_bounds__(256) void enc2_head(
    const int* __restrict__ opt, const int* __restrict__ offs, const int* __restrict__ cnt,
    const int* __restrict__ elist, const float* __restrict__ C2, const float* __restrict__ bg,
    const float* __restrict__ w_qkv2, const float* __restrict__ b_qkv2,
    const float* __restrict__ w_o2, const float* __restrict__ b_o2,
    const float* __restrict__ g2a, const float* __restrict__ bb2a,
    float* __restrict__ x21)
{
    __shared__ float X[4][64];
    __shared__ float QKV[4][192];
    __shared__ float T[4][64];
    int b = blockIdx.x;
    int w = threadIdx.x >> 6, l = threadIdx.x & 63;
    int row = b * 4 + w;

    {
        int d = opt[row];
        float acc = bg[l] + C2[(size_t)d * 128 + 64 + l];
        int base = offs[d], c = cnt[d];
        for (int i = 0; i < c; i++) {
            int s = elist[base + i];
            acc += C2[(size_t)s * 128 + l];
        }
        X[w][l] = acc;
    }
    __syncthreads();

#pragma unroll
    for (int j = 0; j < 3; j++) {
        int n = l + j * 64;
        const float* wr = w_qkv2 + (size_t)n * 64;
        float s = b_qkv2[n];
        for (int k = 0; k < 64; k++) s += X[w][k] * wr[k];
        QKV[w][n] = s;
    }
    __syncthreads();

    {
        float q = QKV[w][l];
        float p0 = q * QKV[0][64 + l], p1 = q * QKV[1][64 + l];
        float p2 = q * QKV[2][64 + l], p3 = q * QKV[3][64 + l];
#pragma unroll
        for (int off = 1; off < 32; off <<= 1) {
            p0 += __shfl_xor(p0, off, 64); p1 += __shfl_xor(p1, off, 64);
            p2 += __shfl_xor(p2, off, 64); p3 += __shfl_xor(p3, off, 64);
        }
        p0 *= 0.1767766953f; p1 *= 0.1767766953f; p2 *= 0.1767766953f; p3 *= 0.1767766953f;
        float mx = fmaxf(fmaxf(p0, p1), fmaxf(p2, p3));
        float e0 = __expf(p0 - mx), e1 = __expf(p1 - mx), e2 = __expf(p2 - mx), e3 = __expf(p3 - mx);
        float inv = 1.f / (e0 + e1 + e2 + e3);
        T[w][l] = (e0 * QKV[0][128 + l] + e1 * QKV[1][128 + l] +
                   e2 * QKV[2][128 + l] + e3 * QKV[3][128 + l]) * inv;
    }
    __syncthreads();

    {
        const float* wr = w_o2 + (size_t)l * 64;
        float s = b_o2[l];
        for (int k = 0; k < 64; k++) s += T[w][k] * wr[k];
        float xa = s + X[w][l];
        float sum = xa, sq = xa * xa;
#pragma unroll
        for (int off = 1; off < 64; off <<= 1) {
            sum += __shfl_xor(sum, off, 64);
            sq  += __shfl_xor(sq, off, 64);
        }
        float m = sum * (1.f / 64.f);
        float ri = rsqrtf(sq * (1.f / 64.f) - m * m + 1e-5f);
        x21[(size_t)row * 64 + l] = g2a[l] * (xa - m) * ri + bb2a[l];
    }
}

// ---------------------------------------------------------------------------
// ff_fused: ff1(relu) + ff2 + LN(g2b) + l1(tanh) + l2. One block per row.
__global__ __launch_bounds__(256) void ff_fused(
    const float* __restrict__ x21, const float* __restrict__ wf1, const float* __restrict__ bf1,
    const float* __restrict__ wf2, const float* __restrict__ bf2,
    const float* __restrict__ g2b, const float* __restrict__ bb2b,
    const float* __restrict__ w_l1, const float* __restrict__ b_l1,
    const float* __restrict__ w_l2, const float* __restrict__ b_l2,
    float* __restrict__ out)
{
    __shared__ float X[64];
    __shared__ float HL[2048];
    __shared__ float part[4][64];
    __shared__ float X2[64];
    int r = blockIdx.x, t = threadIdx.x;
    int w = t >> 6, l = t & 63;

    if (t < 64) X[t] = x21[(size_t)r * 64 + t];
    __syncthreads();

#pragma unroll
    for (int j = 0; j < 8; j++) {
        int n = t + j * 256;
        const float4* wr4 = (const float4*)(wf1 + (size_t)n * 64);
        float s = bf1[n];
#pragma unroll
        for (int k4 = 0; k4 < 16; k4++) {
            float4 wv = wr4[k4];
            s += wv.x * X[k4 * 4] + wv.y * X[k4 * 4 + 1] + wv.z * X[k4 * 4 + 2] + wv.w * X[k4 * 4 + 3];
        }
        HL[n] = fmaxf(s, 0.f);
    }
    __syncthreads();

    {
        const float4* wr4 = (const float4*)(wf2 + (size_t)l * 2048 + w * 512);
        const float* hp = HL + w * 512;
        float s = 0.f;
#pragma unroll 16
        for (int k4 = 0; k4 < 128; k4++) {
            float4 wv = wr4[k4];
            s += wv.x * hp[k4 * 4] + wv.y * hp[k4 * 4 + 1] + wv.z * hp[k4 * 4 + 2] + wv.w * hp[k4 * 4 + 3];
        }
        part[w][l] = s;
    }
    __syncthreads();

    if (w == 0) {
        float xa = part[0][l] + part[1][l] + part[2][l] + part[3][l] + bf2[l]
                 + x21[(size_t)r * 64 + l];
        float sum = xa, sq = xa * xa;
#pragma unroll
        for (int off = 1; off < 64; off <<= 1) {
            sum += __shfl_xor(sum, off, 64);
            sq  += __shfl_xor(sq, off, 64);
        }
        float m = sum * (1.f / 64.f);
        float ri = rsqrtf(sq * (1.f / 64.f) - m * m + 1e-5f);
        X2[l] = g2b[l] * (xa - m) * ri + bb2b[l];
        __builtin_amdgcn_wave_barrier();
        const float* wr = w_l1 + (size_t)l * 64;
        float s = b_l1[l];
        for (int k = 0; k < 64; k++) s += X2[k] * wr[k];
        float tv = tanhf(s);
        float p = tv * w_l2[l];
#pragma unroll
        for (int off = 1; off < 64; off <<= 1) p += __shfl_xor(p, off, 64);
        if (l == 0) out[r] = p + b_l2[0];
    }
}

// ---------------------------------------------------------------------------
extern "C" void kernel_launch(void* const* d_in, const int* in_sizes, int n_in,
                              void* d_out, int out_size, void* d_ws, size_t ws_size,
                              hipStream_t stream)
{
    const float* nodes  = (const float*)d_in[0];
    const int*   ei     = (const int*)d_in[1];
    const int*   opt    = (const int*)d_in[2];
    const float* w_qkv1 = (const float*)d_in[3];
    const float* b_qkv1 = (const float*)d_in[4];
    const float* w_o1   = (const float*)d_in[5];
    const float* b_o1   = (const float*)d_in[6];
    const float* g1a    = (const float*)d_in[7];
    const float* bb1a   = (const float*)d_in[8];
    const float* w_ff1a = (const float*)d_in[9];
    const float* bf1a   = (const float*)d_in[10];
    const float* w_ff1b = (const float*)d_in[11];
    const float* bf1b   = (const float*)d_in[12];
    const float* g1b    = (const float*)d_in[13];
    const float* bb1b   = (const float*)d_in[14];
    // d_in[15..28]: wq..b6 — dead code (edge_type ≡ 0: softmax over singleton axis)
    const float* w_rel  = (const float*)d_in[29];
    const float* w_root = (const float*)d_in[30];
    const float* b_rgcn = (const float*)d_in[31];
    const float* wg_rel = (const float*)d_in[32];
    const float* wg_root= (const float*)d_in[33];
    const float* bg     = (const float*)d_in[34];
    const float* w_qkv2 = (const float*)d_in[35];
    const float* b_qkv2 = (const float*)d_in[36];
    const float* w_o2   = (const float*)d_in[37];
    const float* b_o2   = (const float*)d_in[38];
    const float* g2a    = (const float*)d_in[39];
    const float* bb2a   = (const float*)d_in[40];
    const float* w_ff2a = (const float*)d_in[41];
    const float* bf2a   = (const float*)d_in[42];
    const float* w_ff2b = (const float*)d_in[43];
    const float* bf2b   = (const float*)d_in[44];
    const float* g2b    = (const float*)d_in[45];
    const float* bb2b   = (const float*)d_in[46];
    const float* w_l1   = (const float*)d_in[47];
    const float* b_l1   = (const float*)d_in[48];
    const float* w_l2   = (const float*)d_in[49];
    const float* b_l2   = (const float*)d_in[50];

    const int H = 768, F = 2048;
    const int Nn = in_sizes[0] / H;            // 20000
    const int E  = in_sizes[1] / 2;            // 40000
    const int R  = in_sizes[2];                // 256 option rows
    const int Mpad = (Nn + 127) & ~127;        // 20096

    char* ws = (char*)d_ws;
    size_t off = 0;
    auto alloc = [&](size_t b) -> char* {
        char* p = ws + off; off += (b + 255) & ~(size_t)255; return p;
    };
    // bf16 weights
    u16* wqkv1b  = (u16*)alloc((size_t)3 * H * H * 2);
    u16* wo1b    = (u16*)alloc((size_t)H * H * 2);
    u16* wff1ab  = (u16*)alloc((size_t)F * H * 2);
    u16* wff1bb  = (u16*)alloc((size_t)H * F * 2);
    u16* Wbraw   = (u16*)alloc((size_t)1536 * H * 2);     // [w_root ; w_rel0] row-major bf16
    u16* W2tb    = (u16*)alloc((size_t)128 * H * 2);      // [wg_rel^T ; wg_root^T]
    u16* WcT     = (u16*)alloc((size_t)128 * 1536 * 2);   // (Wb @ W2)^T  bf16
    float* bc    = (float*)alloc((size_t)128 * 4);        // b_rgcn @ W2
    // split-K partial buffer (max = qkv 4x256x2304)
    float* Psk  = (float*)alloc((size_t)4 * 256 * 2304 * 4);
    // encoder1 activations
    float* x0   = (float*)alloc((size_t)R * H * 4);
    u16*  x0b   = (u16*)alloc((size_t)R * H * 2);
    u16*  atnob = (u16*)alloc((size_t)R * H * 2);
    float* x1   = (float*)alloc((size_t)R * H * 4);
    u16*  x1b   = (u16*)alloc((size_t)R * H * 2);
    u16*  ffhb  = (u16*)alloc((size_t)R * F * 2);
    // big buffers
    u16*  Abig  = (u16*)alloc((size_t)Mpad * 1536 * 2);   // [nodes2 | aggN] bf16
    float* C2   = (float*)alloc((size_t)Mpad * 128 * 4);
    // CSR
    int* cnt   = (int*)alloc((size_t)Nn * 4);
    int* offs  = (int*)alloc((size_t)Nn * 4);
    int* cur   = (int*)alloc((size_t)Nn * 4);
    int* elist = (int*)alloc((size_t)E * 4);
    int* btot  = (int*)alloc((size_t)64 * 4);
    // tail
    float* x21 = (float*)alloc((size_t)R * 64 * 4);
    (void)ws_size; (void)n_in; (void)out_size;

    // 1. weight conversions
    {
        CJobs6 cj;
        cj.j[0] = { w_qkv1, wqkv1b, (long)3 * H * H / 4 };
        cj.j[1] = { w_o1,   wo1b,   (long)H * H / 4 };
        cj.j[2] = { w_ff1a, wff1ab, (long)F * H / 4 };
        cj.j[3] = { w_ff1b, wff1bb, (long)H * F / 4 };
        cj.j[4] = { w_root, Wbraw,                 (long)H * H / 4 };
        cj.j[5] = { w_rel,  Wbraw + (size_t)H * H, (long)H * H / 4 };   // w_rel[0] only
        conv6_bf16<<<dim3(432, 1, 6), 256, 0, stream>>>(cj);
    }
    // 2. transposes + bc
    {
        TJob t0 = { wg_rel,  W2tb,                    768, 64, 768 };
        TJob t1 = { wg_root, W2tb + (size_t)64 * 768, 768, 64, 768 };
        prep2<<<dim3(2, 24, 3), 256, 0, stream>>>(t0, t1, b_rgcn, wg_rel, wg_root, bc);
    }
    // 3-4. WcT = (Wb@W2)^T via split-K + reduce
    gemm_bt_sk<<<dim3(12, 1, 4), 256, 0, stream>>>(W2tb, Wbraw, Psk, 128, 1536, 768, 192);
    sk_reduce_b<<<768, 256, 0, stream>>>(Psk, 4, (long)128 * 1536, 1536, nullptr, 0, WcT);

    // 5. nodes -> Abig cols 0:768 + gather option rows
    conv_nodes_gx<<<2048 + R, 256, 0, stream>>>(nodes, Abig, Nn, Mpad, opt, x0, x0b);

    // 6. encoder layer 1: ONE cooperative kernel
    {
        Enc1Args ea;
        ea.x0b = x0b; ea.wqkv1b = wqkv1b; ea.wo1b = wo1b; ea.wff1ab = wff1ab; ea.wff1bb = wff1bb;
        ea.b_qkv1 = b_qkv1; ea.b_o1 = b_o1; ea.g1a = g1a; ea.bb1a = bb1a;
        ea.bf1a = bf1a; ea.bf1b = bf1b; ea.g1b = g1b; ea.bb1b = bb1b; ea.x0 = x0;
        ea.Psk = Psk; ea.x1 = x1;
        ea.x1b = x1b; ea.atnob = atnob; ea.ffhb = ffhb; ea.Abig = Abig;
        ea.opt = opt;
        void* kp[] = { &ea };
        hipLaunchCooperativeKernel((void*)enc1_coop, dim3(144), dim3(256), kp, 0, stream);
    }

    // 7. CSR build: ONE cooperative kernel
    {
        CsrArgs ca;
        ca.ei = ei; ca.cnt = cnt; ca.offs = offs; ca.cur = cur; ca.elist = elist;
        ca.btot = btot; ca.Nn = Nn; ca.E = E;
        void* kp[] = { &ca };
        hipLaunchCooperativeKernel((void*)csr_coop, dim3(40), dim3(1024), kp, 0, stream);
    }

    // 8. mean-aggregate nodes2 into Abig cols 768:1536
    gather_mean<<<Mpad / 4, 256, 0, stream>>>(offs, cnt, elist, Abig, Nn, Mpad);

    // 9. fused RGCN+GraphConv projection: C2 = Abig @ Wc + bc
    gemm_bt<<<dim3(1, Mpad / 128), 256, 0, stream>>>(Abig, WcT, C2, nullptr, bc, Mpad, 128, 1536, 0);

    // 10-11. tail
    enc2_head<<<R / 4, 256, 0, stream>>>(opt, offs, cnt, elist, C2, bg,
                                         w_qkv2, b_qkv2, w_o2, b_o2, g2a, bb2a, x21);
    ff_fused<<<R, 256, 0, stream>>>(x21, w_ff2a, bf2a, w_ff2b, bf2b, g2b, bb2b,
                                    w_l1, b_l1, w_l2, b_l2, (float*)d_out);
}